// Round 10
// baseline (788.082 us; speedup 1.0000x reference)
//
#include <hip/hip_runtime.h>

#define NB 20000
#define EB 320000
#define DIN 128
#define H1D 256
#define H2D 256
#define DOUTD 128
#define SCAN_BLOCKS ((NB + 255) / 256)   // 79
#define MT 157                           // ceil(20000/128) row tiles

typedef __attribute__((ext_vector_type(4))) float fvec4;

template <bool NT>
__device__ inline float4 ld4(const float* p) {
    if (NT) {
        fvec4 v = __builtin_nontemporal_load((const fvec4*)p);
        return make_float4(v.x, v.y, v.z, v.w);
    }
    return *(const float4*)p;
}
template <bool NT>
__device__ inline void st4(float* p, float4 v) {
    if (NT) {
        fvec4 t; t.x = v.x; t.y = v.y; t.z = v.z; t.w = v.w;
        __builtin_nontemporal_store(t, (fvec4*)p);
    } else {
        *(float4*)p = v;
    }
}

// ---------------------------------------------------------------------------
// CSR build: histogram -> 3-phase scan -> dinv -> counting-sort scatter into
// int2{src, w_bits} edge records sorted by dst. (unchanged, ~25 us)
// ---------------------------------------------------------------------------

__global__ void zero_kernel(int* __restrict__ p, int n) {
    int t = blockIdx.x * blockDim.x + threadIdx.x;
    if (t < n) p[t] = 0;
}

__global__ void hist_kernel(const int* __restrict__ dst, int* __restrict__ bins) {
    int t = blockIdx.x * blockDim.x + threadIdx.x;
    if (t < EB) atomicAdd(&bins[dst[t]], 1);
}

__global__ __launch_bounds__(256) void scanA_kernel(const int* __restrict__ bins,
                                                    int* __restrict__ loc,
                                                    int* __restrict__ blksum) {
    __shared__ int s[256];
    int t = threadIdx.x;
    int i = blockIdx.x * 256 + t;
    int v = (i < NB) ? bins[i] : 0;
    s[t] = v;
    __syncthreads();
    for (int off = 1; off < 256; off <<= 1) {
        int u = (t >= off) ? s[t - off] : 0;
        __syncthreads();
        s[t] += u;
        __syncthreads();
    }
    if (i < NB) loc[i] = s[t] - v;
    if (t == 255) blksum[blockIdx.x] = s[255];
}

__global__ __launch_bounds__(128) void scanB_kernel(int* __restrict__ blksum) {
    __shared__ int s[128];
    int t = threadIdx.x;
    int v = (t < SCAN_BLOCKS) ? blksum[t] : 0;
    s[t] = v;
    __syncthreads();
    for (int off = 1; off < 128; off <<= 1) {
        int u = (t >= off) ? s[t - off] : 0;
        __syncthreads();
        s[t] += u;
        __syncthreads();
    }
    if (t < SCAN_BLOCKS) blksum[t] = s[t] - v;
}

__global__ __launch_bounds__(256) void scanC_kernel(const int* __restrict__ bins,
                                                    const int* __restrict__ loc,
                                                    const int* __restrict__ blksum,
                                                    int* __restrict__ rs,
                                                    int* __restrict__ cursor,
                                                    float* __restrict__ dinv) {
    int i = blockIdx.x * 256 + threadIdx.x;
    if (i < NB) {
        int r = loc[i] + blksum[blockIdx.x];
        rs[i] = r;
        cursor[i] = r;
        dinv[i] = rsqrtf((float)bins[i] + 1.0f);  // deg = in-degree + 1 (self loop)
    }
    if (i == 0) rs[NB] = EB;
}

__global__ void scatter_kernel(const int* __restrict__ src, const int* __restrict__ dst,
                               const float* __restrict__ dinv,
                               int* __restrict__ cursor, int2* __restrict__ edges) {
    int t = blockIdx.x * blockDim.x + threadIdx.x;
    if (t < EB) {
        int d = dst[t], s = src[t];
        int p = atomicAdd(&cursor[d], 1);
        edges[p] = make_int2(s, __float_as_int(dinv[s] * dinv[d]));
    }
}

// ---------------------------------------------------------------------------
// Per-batch sliced aggregation (v2, at the gather-byte ceiling). A virtual
// slice = 32 consecutive floats = one 128B line; 8 slices per dispatch:
// F=128: 4 col-slices x 2 dst-node halves; F=256: 8 col-slices. Slice ss is
// bound to blocks with dispatch blockIdx%8==ss -> per-XCD gather window =
// 20000 x 128B = 2.56 MB, L2-resident (FETCH confirmed 315->51 MB).
// 5 nodes/wave, cached edge loads, 8-edge unroll (4 indep chains), 32-lane
// half per line, wave-uniform bounds. In/out are plain [20000][F] rows.
// ---------------------------------------------------------------------------

template <int F, bool BIAS, bool PRELU>
__device__ void aggv_body(int a, int ss,
                          const float* __restrict__ h, float* __restrict__ out,
                          const int* __restrict__ rs, const int2* __restrict__ edges,
                          const float* __restrict__ dinv, const float* __restrict__ bias,
                          const float* __restrict__ pa) {
    constexpr int NS = F / 32;            // col-slices: 4 / 8
    constexpr int NH = 8 / NS;            // dst-node halves: 2 / 1
    const int half = (NH == 2) ? (ss >> 2) : 0;
    const int c32 = ss & (NS - 1);
    const int chunk = a >> 3;
    const int wid = threadIdx.x >> 6;
    const int lane = threadIdx.x & 63;
    const int li = lane & 31;
    const int eh = lane >> 5;
    const int fo = c32 * 32 + li;

    const float* gb = h + fo;
    float* ob = out + fo;
    const float pav = PRELU ? *pa : 0.0f;
    const float bval = BIAS ? bias[fo] : 0.0f;

    int n = half * (NB / NH) + chunk * 20 + wid * 5;
    int e1n = __builtin_amdgcn_readfirstlane(rs[n]);
    for (int j = 0; j < 5; ++j, ++n) {
        int e0 = e1n;
        e1n = __builtin_amdgcn_readfirstlane(rs[n + 1]);
        int e1 = e1n;
        float a0 = 0.f, a1 = 0.f, a2 = 0.f, a3 = 0.f;
        int e = e0;
        for (; e + 8 <= e1; e += 8) {
            int2 r0 = edges[e + eh];
            int2 r1 = edges[e + 2 + eh];
            int2 r2 = edges[e + 4 + eh];
            int2 r3 = edges[e + 6 + eh];
            float t0 = gb[(size_t)r0.x * F];
            float t1 = gb[(size_t)r1.x * F];
            float t2 = gb[(size_t)r2.x * F];
            float t3 = gb[(size_t)r3.x * F];
            a0 = fmaf(t0, __int_as_float(r0.y), a0);
            a1 = fmaf(t1, __int_as_float(r1.y), a1);
            a2 = fmaf(t2, __int_as_float(r2.y), a2);
            a3 = fmaf(t3, __int_as_float(r3.y), a3);
        }
        for (; e + 2 <= e1; e += 2) {
            int2 r0 = edges[e + eh];
            a0 = fmaf(gb[(size_t)r0.x * F], __int_as_float(r0.y), a0);
        }
        if (e < e1) {  // one leftover edge; eh==1 lanes contribute 0
            int my = e + eh;
            bool valid = (my < e1);
            int2 r0 = edges[valid ? my : e];
            float w = valid ? __int_as_float(r0.y) : 0.0f;
            a0 = fmaf(gb[(size_t)r0.x * F], w, a0);
        }
        float acc = (a0 + a1) + (a2 + a3);
        acc += __shfl_xor(acc, 32, 64);
        float dv = dinv[n];
        float r = fmaf(gb[(size_t)n * F], dv * dv, acc);
        if (BIAS) r += bval;
        if (PRELU) r = (r >= 0.0f) ? r : pav * r;
        if (eh == 0) ob[(size_t)n * F] = r;
    }
}

// ---------------------------------------------------------------------------
// FP32 GEMM body (per batch, M=20000): C = A@W (+bias)(+prelu).
// 128x64 tile, BK=16, 8x4 microtile, REGISTER-PREFETCH DOUBLE BUFFER:
// next k-tile is loaded into regs while the FMA loop consumes LDS -> load
// latency hidden (fixes R9's 43% VALU idle). NT: nontemporal A/C so fat-
// dispatch gemm streams don't evict the co-resident agg's L2 window.
// ---------------------------------------------------------------------------
template <bool BIAS, bool PRELU, bool NT>
__device__ void gemm_body(int gx, const float* __restrict__ A, int K,
                          const float* __restrict__ W, int Nc,
                          const float* __restrict__ bias, const float* __restrict__ pa,
                          float* __restrict__ C) {
    __shared__ alignas(16) float As[16][132];
    __shared__ alignas(16) float Bs[16][68];
    const int M = NB;
    int t = threadIdx.x;
    int bm = (gx % MT) * 128;
    int bn = (gx / MT) * 64;
    int tx = t & 15, ty = t >> 4;
    int m0 = ty * 8, n0 = tx * 4;
    int ar = t >> 2, ac4 = (t & 3) * 4;
    int br = t >> 4, bc4 = (t & 15) * 4;
    int r0 = bm + ar, r1 = bm + ar + 64;
    bool v0 = r0 < M, v1 = r1 < M;
    const float* pA0 = A + (size_t)r0 * K + ac4;
    const float* pA1 = A + (size_t)r1 * K + ac4;
    const float* pW = W + (size_t)br * Nc + bn + bc4;

    float4 a0 = make_float4(0.f, 0.f, 0.f, 0.f), a1 = a0;
    if (v0) a0 = ld4<NT>(pA0);
    if (v1) a1 = ld4<NT>(pA1);
    float4 bv = *(const float4*)pW;

    float acc[8][4] = {};

    for (int k0 = 0; k0 < K; k0 += 16) {
        As[ac4 + 0][ar] = a0.x; As[ac4 + 1][ar] = a0.y;
        As[ac4 + 2][ar] = a0.z; As[ac4 + 3][ar] = a0.w;
        As[ac4 + 0][ar + 64] = a1.x; As[ac4 + 1][ar + 64] = a1.y;
        As[ac4 + 2][ar + 64] = a1.z; As[ac4 + 3][ar + 64] = a1.w;
        *(float4*)&Bs[br][bc4] = bv;
        __syncthreads();
        if (k0 + 16 < K) {  // prefetch next tile into regs; lands during FMAs
            a0 = v0 ? ld4<NT>(pA0 + k0 + 16) : make_float4(0.f, 0.f, 0.f, 0.f);
            a1 = v1 ? ld4<NT>(pA1 + k0 + 16) : make_float4(0.f, 0.f, 0.f, 0.f);
            bv = *(const float4*)(pW + (size_t)(k0 + 16) * Nc);
        }
#pragma unroll
        for (int k = 0; k < 16; ++k) {
            float4 av0 = *(const float4*)&As[k][m0];
            float4 av1 = *(const float4*)&As[k][m0 + 4];
            float4 bv4 = *(const float4*)&Bs[k][n0];
            float a_[8] = {av0.x, av0.y, av0.z, av0.w, av1.x, av1.y, av1.z, av1.w};
            float b_[4] = {bv4.x, bv4.y, bv4.z, bv4.w};
#pragma unroll
            for (int i = 0; i < 8; ++i)
#pragma unroll
                for (int j = 0; j < 4; ++j)
                    acc[i][j] = fmaf(a_[i], b_[j], acc[i][j]);
        }
        __syncthreads();
    }

    float pav = 0.0f;
    if (PRELU) pav = *pa;
#pragma unroll
    for (int i = 0; i < 8; ++i) {
        int row = bm + m0 + i;
        if (row < M) {
            float v[4];
#pragma unroll
            for (int j = 0; j < 4; ++j) {
                float x = acc[i][j];
                if (BIAS) x += bias[bn + n0 + j];
                if (PRELU) x = (x >= 0.0f) ? x : pav * x;
                v[j] = x;
            }
            st4<NT>(&C[(size_t)row * Nc + bn + n0], make_float4(v[0], v[1], v[2], v[3]));
        }
    }
}

// ---------------------------------------------------------------------------
// Wrappers: standalone agg, fat (gemm NT || agg), dual-gemm (cached).
// Fat: gemm blocks first (bx<ng); agg tail uses dispatch bx&7 as slice ->
// XCD binding survives; (chunk,ss) coverage bijective since NA%8==0.
// ---------------------------------------------------------------------------

template <int F, bool BIAS, bool PRELU>
__global__ __launch_bounds__(256) void aggv_kernel(
    const float* __restrict__ h, float* __restrict__ out,
    const int* __restrict__ rs, const int2* __restrict__ edges,
    const float* __restrict__ dinv, const float* __restrict__ bias,
    const float* __restrict__ pa) {
    aggv_body<F, BIAS, PRELU>(blockIdx.x, blockIdx.x & 7, h, out, rs, edges,
                              dinv, bias, pa);
}

template <int AF, bool AB, bool AP, bool GB_, bool GP>
__global__ __launch_bounds__(256) void fat_kernel(
    const float* __restrict__ A, int K, const float* __restrict__ W, int Nc,
    const float* __restrict__ gbias, float* __restrict__ C, int ng,
    const float* __restrict__ ah, float* __restrict__ aout,
    const int* __restrict__ rs, const int2* __restrict__ edges,
    const float* __restrict__ dinv, const float* __restrict__ abias,
    const float* __restrict__ pa) {
    int bx = blockIdx.x;
    if (bx < ng) {
        gemm_body<GB_, GP, true>(bx, A, K, W, Nc, gbias, pa, C);
    } else {
        aggv_body<AF, AB, AP>(bx - ng, bx & 7, ah, aout, rs, edges, dinv, abias, pa);
    }
}

template <bool B1, bool P1, bool B2, bool P2>
__global__ __launch_bounds__(256) void gemm2_kernel(
    const float* __restrict__ A1p, int K1, const float* __restrict__ W1p, int N1,
    const float* __restrict__ bias1, float* __restrict__ C1, int ng1,
    const float* __restrict__ A2p, int K2, const float* __restrict__ W2p, int N2,
    const float* __restrict__ bias2, float* __restrict__ C2,
    const float* __restrict__ pa) {
    int bx = blockIdx.x;
    if (bx < ng1) gemm_body<B1, P1, false>(bx, A1p, K1, W1p, N1, bias1, pa, C1);
    else          gemm_body<B2, P2, false>(bx - ng1, A2p, K2, W2p, N2, bias2, pa, C2);
}

// ---------------------------------------------------------------------------

static inline char* carve(char*& p, size_t bytes) {
    char* r = p;
    p += (bytes + 255) & ~(size_t)255;
    return r;
}

extern "C" void kernel_launch(void* const* d_in, const int* in_sizes, int n_in,
                              void* d_out, int out_size, void* d_ws, size_t ws_size,
                              hipStream_t stream) {
    const float* X  = (const float*)d_in[0];
    const float* W1 = (const float*)d_in[1];
    const float* b1 = (const float*)d_in[2];
    const float* W2 = (const float*)d_in[3];
    const float* b2 = (const float*)d_in[4];
    const float* W3 = (const float*)d_in[5];
    const float* b3 = (const float*)d_in[6];
    const float* pa = (const float*)d_in[7];
    const int* ei   = (const int*)d_in[8];
    const int* src = ei;
    const int* dst = ei + EB;
    float* out = (float*)d_out;

    char* p = (char*)d_ws;
    int* bins    = (int*)carve(p, NB * sizeof(int));
    int* loc     = (int*)carve(p, NB * sizeof(int));
    int* blksum  = (int*)carve(p, 128 * sizeof(int));
    int* rs      = (int*)carve(p, (NB + 1) * sizeof(int));
    int* cursor  = (int*)carve(p, NB * sizeof(int));
    int2* edges  = (int2*)carve(p, EB * sizeof(int2));
    float* dinv  = (float*)carve(p, NB * sizeof(float));
    float* P0 = (float*)carve(p, (size_t)NB * 256 * sizeof(float));
    float* Q0 = (float*)carve(p, (size_t)NB * 256 * sizeof(float));
    float* P1 = (float*)carve(p, (size_t)NB * 256 * sizeof(float));
    float* Q1 = (float*)carve(p, (size_t)NB * 256 * sizeof(float));

    const float* X0 = X;
    const float* X1 = X + (size_t)NB * DIN;
    float* out0 = out;
    float* out1 = out + (size_t)NB * DOUTD;

    // --- CSR build ---
    zero_kernel<<<SCAN_BLOCKS, 256, 0, stream>>>(bins, NB);
    hist_kernel<<<(EB + 255) / 256, 256, 0, stream>>>(dst, bins);
    scanA_kernel<<<SCAN_BLOCKS, 256, 0, stream>>>(bins, loc, blksum);
    scanB_kernel<<<1, 128, 0, stream>>>(blksum);
    scanC_kernel<<<SCAN_BLOCKS, 256, 0, stream>>>(bins, loc, blksum, rs, cursor, dinv);
    scatter_kernel<<<(EB + 255) / 256, 256, 0, stream>>>(src, dst, dinv, cursor, edges);

    const int NA128 = 4000;          // 500 chunks x 8 slices (2 halves x 4 cols)
    const int NA256 = 8000;          // 1000 chunks x 8 col-slices
    const int NG256 = MT * 4;        // 628 gemm blocks (N=256)
    const int NG128 = MT * 2;        // 314 gemm blocks (N=128)

    // Per-batch chain A1->G1->G2->A2->G3->A3, batches staggered by one stage.

    // D1: A1(b0): X0 -> P0 [F=128]
    aggv_kernel<128, false, false><<<NA128, 256, 0, stream>>>(
        X0, P0, rs, edges, dinv, nullptr, nullptr);

    // D2: G1(b0): P0@W1(+b1,prelu) -> Q0  ||  A1(b1): X1 -> P1
    fat_kernel<128, false, false, true, true><<<NG256 + NA128, 256, 0, stream>>>(
        P0, DIN, W1, H1D, b1, Q0, NG256,
        X1, P1, rs, edges, dinv, nullptr, pa);

    // D3: G2(b0): Q0@W2 -> P0  ;  G1(b1): P1@W1(+b1,prelu) -> Q1  (one dispatch)
    gemm2_kernel<false, false, true, true><<<NG256 + NG256, 256, 0, stream>>>(
        Q0, H1D, W2, H2D, nullptr, P0, NG256,
        P1, DIN, W1, H1D, b1, Q1, pa);

    // D4: G2(b1): Q1@W2 -> P1  ||  A2(b0): P0 -> Q0 (+b2,prelu) [F=256]
    fat_kernel<256, true, true, false, false><<<NG256 + NA256, 256, 0, stream>>>(
        Q1, H1D, W2, H2D, nullptr, P1, NG256,
        P0, Q0, rs, edges, dinv, b2, pa);

    // D5: G3(b0): Q0@W3 -> P0  ||  A2(b1): P1 -> Q1 (+b2,prelu) [F=256]
    fat_kernel<256, true, true, false, false><<<NG128 + NA256, 256, 0, stream>>>(
        Q0, H2D, W3, DOUTD, nullptr, P0, NG128,
        P1, Q1, rs, edges, dinv, b2, pa);

    // D6: G3(b1): Q1@W3 -> P1  ||  A3(b0): P0 -> out0 (+b3) [F=128]
    fat_kernel<128, true, false, false, false><<<NG128 + NA128, 256, 0, stream>>>(
        Q1, H2D, W3, DOUTD, nullptr, P1, NG128,
        P0, out0, rs, edges, dinv, b3, pa);

    // D7: A3(b1): P1 -> out1 (+b3) [F=128]
    aggv_kernel<128, true, false><<<NA128, 256, 0, stream>>>(
        P1, out1, rs, edges, dinv, b3, nullptr);
}

// Round 11
// 442.085 us; speedup vs baseline: 1.7826x; 1.7826x over previous
//
#include <hip/hip_runtime.h>

#define NB 20000
#define EB 320000
#define DIN 128
#define H1D 256
#define H2D 256
#define DOUTD 128
#define SCAN_BLOCKS ((NB + 255) / 256)   // 79

typedef __attribute__((ext_vector_type(8))) short short8;    // 8 bf16 (4 VGPR)
typedef __attribute__((ext_vector_type(4))) float f32x4;     // MFMA acc

// Split fp32 into bf16 hi + bf16 lo (round-to-nearest-even each).
__device__ inline void bsplit(float x, unsigned short& h, unsigned short& l) {
    unsigned u = __float_as_uint(x);
    unsigned hr = (u + 0x7FFFu + ((u >> 16) & 1u)) & 0xFFFF0000u;
    h = (unsigned short)(hr >> 16);
    float lo = x - __uint_as_float(hr);
    unsigned v = __float_as_uint(lo);
    l = (unsigned short)((v + 0x7FFFu + ((v >> 16) & 1u)) >> 16);
}

// ---------------------------------------------------------------------------
// CSR build (unchanged): histogram -> 3-phase scan -> dinv -> counting-sort
// scatter into int2{src, w_bits} edge records sorted by dst.
// ---------------------------------------------------------------------------

__global__ void zero_kernel(int* __restrict__ p, int n) {
    int t = blockIdx.x * blockDim.x + threadIdx.x;
    if (t < n) p[t] = 0;
}

__global__ void hist_kernel(const int* __restrict__ dst, int* __restrict__ bins) {
    int t = blockIdx.x * blockDim.x + threadIdx.x;
    if (t < EB) atomicAdd(&bins[dst[t]], 1);
}

__global__ __launch_bounds__(256) void scanA_kernel(const int* __restrict__ bins,
                                                    int* __restrict__ loc,
                                                    int* __restrict__ blksum) {
    __shared__ int s[256];
    int t = threadIdx.x;
    int i = blockIdx.x * 256 + t;
    int v = (i < NB) ? bins[i] : 0;
    s[t] = v;
    __syncthreads();
    for (int off = 1; off < 256; off <<= 1) {
        int u = (t >= off) ? s[t - off] : 0;
        __syncthreads();
        s[t] += u;
        __syncthreads();
    }
    if (i < NB) loc[i] = s[t] - v;
    if (t == 255) blksum[blockIdx.x] = s[255];
}

__global__ __launch_bounds__(128) void scanB_kernel(int* __restrict__ blksum) {
    __shared__ int s[128];
    int t = threadIdx.x;
    int v = (t < SCAN_BLOCKS) ? blksum[t] : 0;
    s[t] = v;
    __syncthreads();
    for (int off = 1; off < 128; off <<= 1) {
        int u = (t >= off) ? s[t - off] : 0;
        __syncthreads();
        s[t] += u;
        __syncthreads();
    }
    if (t < SCAN_BLOCKS) blksum[t] = s[t] - v;
}

__global__ __launch_bounds__(256) void scanC_kernel(const int* __restrict__ bins,
                                                    const int* __restrict__ loc,
                                                    const int* __restrict__ blksum,
                                                    int* __restrict__ rs,
                                                    int* __restrict__ cursor,
                                                    float* __restrict__ dinv) {
    int i = blockIdx.x * 256 + threadIdx.x;
    if (i < NB) {
        int r = loc[i] + blksum[blockIdx.x];
        rs[i] = r;
        cursor[i] = r;
        dinv[i] = rsqrtf((float)bins[i] + 1.0f);  // deg = in-degree + 1 (self loop)
    }
    if (i == 0) rs[NB] = EB;
}

__global__ void scatter_kernel(const int* __restrict__ src, const int* __restrict__ dst,
                               const float* __restrict__ dinv,
                               int* __restrict__ cursor, int2* __restrict__ edges) {
    int t = blockIdx.x * blockDim.x + threadIdx.x;
    if (t < EB) {
        int d = dst[t], s = src[t];
        int p = atomicAdd(&cursor[d], 1);
        edges[p] = make_int2(s, __float_as_int(dinv[s] * dinv[d]));
    }
}

// Transpose + hi/lo-split a weight matrix: W[K][Nc] fp32 -> Wth/Wtl [Nc][K] bf16.
__global__ void wcvt_kernel(const float* __restrict__ W,
                            unsigned short* __restrict__ Wth,
                            unsigned short* __restrict__ Wtl, int K, int Nc) {
    int i = blockIdx.x * 256 + threadIdx.x;
    if (i < K * Nc) {
        int k = i / Nc, n = i % Nc;
        unsigned short h, l;
        bsplit(W[i], h, l);
        Wth[(size_t)n * K + k] = h;
        Wtl[(size_t)n * K + k] = l;
    }
}

// ---------------------------------------------------------------------------
// Sliced aggregation (R9-proven, ~58us/dispatch at the L2-gather ceiling).
// OUT=0: fp32 out; OUT=1: bf16 hi/lo pair out (feeds the MFMA GEMM) -- the
// fp32->bf16x2 split is fused here so no extra conversion pass is needed.
// Pair output is always the interleaved [2n+b][F] layout (row stride 2F).
// ---------------------------------------------------------------------------

template <int F, bool SPLIT_IN, bool SPLIT_OUT, bool BIAS, bool PRELU, int OUT>
__global__ __launch_bounds__(256) void aggv_kernel(
    const float* __restrict__ h, float* __restrict__ out,
    unsigned short* __restrict__ oh, unsigned short* __restrict__ ol,
    const int* __restrict__ rs, const int2* __restrict__ edges,
    const float* __restrict__ dinv, const float* __restrict__ bias,
    const float* __restrict__ pa, int phase) {
    const int ss = blockIdx.x & 7;
    const int chunk = blockIdx.x >> 3;    // [0, 1000)
    const int wid = threadIdx.x >> 6;
    const int lane = threadIdx.x & 63;
    const int li = lane & 31;
    const int eh = lane >> 5;
    const int b = ss >> 2;
    const int c32 = (ss & 3) + phase * 4;
    const int fo = c32 * 32 + li;

    constexpr size_t GS = SPLIT_IN ? F : 2 * F;
    constexpr size_t OS = SPLIT_OUT ? F : 2 * F;
    const float* gb = h + (SPLIT_IN ? (size_t)b * NB * F : (size_t)b * F) + fo;
    float* ob = nullptr;
    unsigned short* ohb = nullptr;
    unsigned short* olb = nullptr;
    if (OUT == 0) {
        ob = out + (SPLIT_OUT ? (size_t)b * NB * F : (size_t)b * F) + fo;
    } else {
        ohb = oh + (size_t)b * F + fo;    // pair out: interleaved, stride 2F
        olb = ol + (size_t)b * F + fo;
    }

    const float pav = PRELU ? *pa : 0.0f;
    const float bval = BIAS ? bias[fo] : 0.0f;

    int n = chunk * 20 + wid * 5;
    int e1n = __builtin_amdgcn_readfirstlane(rs[n]);
    for (int j = 0; j < 5; ++j, ++n) {
        int e0 = e1n;
        e1n = __builtin_amdgcn_readfirstlane(rs[n + 1]);
        int e1 = e1n;
        float a0 = 0.f, a1 = 0.f, a2 = 0.f, a3 = 0.f;
        int e = e0;
        for (; e + 8 <= e1; e += 8) {
            int2 r0 = edges[e + eh];
            int2 r1 = edges[e + 2 + eh];
            int2 r2 = edges[e + 4 + eh];
            int2 r3 = edges[e + 6 + eh];
            float t0 = gb[(size_t)r0.x * GS];
            float t1 = gb[(size_t)r1.x * GS];
            float t2 = gb[(size_t)r2.x * GS];
            float t3 = gb[(size_t)r3.x * GS];
            a0 = fmaf(t0, __int_as_float(r0.y), a0);
            a1 = fmaf(t1, __int_as_float(r1.y), a1);
            a2 = fmaf(t2, __int_as_float(r2.y), a2);
            a3 = fmaf(t3, __int_as_float(r3.y), a3);
        }
        for (; e + 2 <= e1; e += 2) {
            int2 r0 = edges[e + eh];
            a0 = fmaf(gb[(size_t)r0.x * GS], __int_as_float(r0.y), a0);
        }
        if (e < e1) {
            int my = e + eh;
            bool valid = (my < e1);
            int2 r0 = edges[valid ? my : e];
            float w = valid ? __int_as_float(r0.y) : 0.0f;
            a0 = fmaf(gb[(size_t)r0.x * GS], w, a0);
        }
        float acc = (a0 + a1) + (a2 + a3);
        acc += __shfl_xor(acc, 32, 64);
        float dv = dinv[n];
        float r = fmaf(gb[(size_t)n * GS], dv * dv, acc);
        if (BIAS) r += bval;
        if (PRELU) r = (r >= 0.0f) ? r : pav * r;
        if (eh == 0) {
            if (OUT == 0) {
                ob[(size_t)n * OS] = r;
            } else {
                unsigned short hh, ll;
                bsplit(r, hh, ll);
                ohb[(size_t)n * 2 * F] = hh;
                olb[(size_t)n * 2 * F] = ll;
            }
        }
    }
}

// ---------------------------------------------------------------------------
// bf16x3 MFMA GEMM: C = (Ah+Al)@(Wh+Wl) ~= Ah*Wh + Ah*Wl + Al*Wh, fp32 acc.
// A: [M][K] bf16 hi/lo row-major. W: pre-transposed [Nc][K] bf16 hi/lo.
// Block 256 thr = 4 waves; tile BM=128 BN=64 BK=32; wave w owns rows
// [w*32,w*32+32) x all 64 cols = 2x4 tiles of 16x16; 3 MFMA each per k-chunk.
// LDS rows padded to 40 bf16 (80B = 5x16B: aligned b128, ~2-way banks).
// mfma_f32_16x16x32_bf16 layouts: A lane l -> A[l&15][(l>>4)*8+j];
// B lane l -> B[(l>>4)*8+j][l&15] (read from W^T so contiguous);
// D lane l reg j -> D[(l>>4)*4+j][l&15]  [guide m89/m91-verified].
// OM=0: fp32 C out. OM=1: bf16 hi/lo pair out (feeds next GEMM).
// ---------------------------------------------------------------------------
template <bool BIAS, bool PRELU, int OM>
__global__ __launch_bounds__(256) void gemmb_kernel(
    const unsigned short* __restrict__ Ah, const unsigned short* __restrict__ Al, int K,
    const unsigned short* __restrict__ Wth, const unsigned short* __restrict__ Wtl, int Nc,
    const float* __restrict__ bias, const float* __restrict__ pa,
    float* __restrict__ C, unsigned short* __restrict__ Ch, unsigned short* __restrict__ Cl) {
    const int M = 2 * NB;
    __shared__ unsigned short Ash[128][40];
    __shared__ unsigned short Asl[128][40];
    __shared__ unsigned short Bsh[64][40];
    __shared__ unsigned short Bsl[64][40];

    const int t = threadIdx.x;
    const int bm = blockIdx.x * 128;
    const int bn = blockIdx.y * 64;
    const int w = t >> 6;
    const int l = t & 63;
    const int lm = l & 15;
    const int lk = (l >> 4) * 8;

    f32x4 acc[2][4];
#pragma unroll
    for (int m = 0; m < 2; ++m)
#pragma unroll
        for (int nt = 0; nt < 4; ++nt) acc[m][nt] = (f32x4){0.f, 0.f, 0.f, 0.f};

    for (int k0 = 0; k0 < K; k0 += 32) {
        // stage A (128x32 hi+lo): 2 chunks of 16B per thread per array
#pragma unroll
        for (int i = 0; i < 2; ++i) {
            int c = t + i * 256;
            int row = c >> 2, seg = (c & 3) * 8;
            int gr = bm + row;
            short8 vh = (short8){0, 0, 0, 0, 0, 0, 0, 0};
            short8 vl = vh;
            if (gr < M) {
                vh = *(const short8*)&Ah[(size_t)gr * K + k0 + seg];
                vl = *(const short8*)&Al[(size_t)gr * K + k0 + seg];
            }
            *(short8*)&Ash[row][seg] = vh;
            *(short8*)&Asl[row][seg] = vl;
        }
        // stage B (64x32 hi+lo) from W^T rows: 1 chunk per thread per array
        {
            int n = t >> 2, seg = (t & 3) * 8;
            *(short8*)&Bsh[n][seg] = *(const short8*)&Wth[(size_t)(bn + n) * K + k0 + seg];
            *(short8*)&Bsl[n][seg] = *(const short8*)&Wtl[(size_t)(bn + n) * K + k0 + seg];
        }
        __syncthreads();

        short8 ah0 = *(const short8*)&Ash[w * 32 + lm][lk];
        short8 ah1 = *(const short8*)&Ash[w * 32 + 16 + lm][lk];
        short8 al0 = *(const short8*)&Asl[w * 32 + lm][lk];
        short8 al1 = *(const short8*)&Asl[w * 32 + 16 + lm][lk];
#pragma unroll
        for (int nt = 0; nt < 4; ++nt) {
            short8 bh = *(const short8*)&Bsh[nt * 16 + lm][lk];
            short8 bl = *(const short8*)&Bsl[nt * 16 + lm][lk];
            acc[0][nt] = __builtin_amdgcn_mfma_f32_16x16x32_bf16(ah0, bh, acc[0][nt], 0, 0, 0);
            acc[0][nt] = __builtin_amdgcn_mfma_f32_16x16x32_bf16(ah0, bl, acc[0][nt], 0, 0, 0);
            acc[0][nt] = __builtin_amdgcn_mfma_f32_16x16x32_bf16(al0, bh, acc[0][nt], 0, 0, 0);
            acc[1][nt] = __builtin_amdgcn_mfma_f32_16x16x32_bf16(ah1, bh, acc[1][nt], 0, 0, 0);
            acc[1][nt] = __builtin_amdgcn_mfma_f32_16x16x32_bf16(ah1, bl, acc[1][nt], 0, 0, 0);
            acc[1][nt] = __builtin_amdgcn_mfma_f32_16x16x32_bf16(al1, bh, acc[1][nt], 0, 0, 0);
        }
        __syncthreads();
    }

    const float pav = PRELU ? *pa : 0.0f;
    const int lg = l >> 4;
#pragma unroll
    for (int m = 0; m < 2; ++m) {
#pragma unroll
        for (int nt = 0; nt < 4; ++nt) {
            int col = bn + nt * 16 + lm;
            float bv = BIAS ? bias[col] : 0.0f;
#pragma unroll
            for (int j = 0; j < 4; ++j) {
                int row = bm + w * 32 + m * 16 + lg * 4 + j;
                if (row < M) {
                    float r = acc[m][nt][j] + bv;
                    if (PRELU) r = (r >= 0.0f) ? r : pav * r;
                    if (OM == 0) {
                        C[(size_t)row * Nc + col] = r;
                    } else {
                        unsigned short hh, ll;
                        bsplit(r, hh, ll);
                        Ch[(size_t)row * Nc + col] = hh;
                        Cl[(size_t)row * Nc + col] = ll;
                    }
                }
            }
        }
    }
}

// ---------------------------------------------------------------------------

static inline char* carve(char*& p, size_t bytes) {
    char* r = p;
    p += (bytes + 255) & ~(size_t)255;
    return r;
}

extern "C" void kernel_launch(void* const* d_in, const int* in_sizes, int n_in,
                              void* d_out, int out_size, void* d_ws, size_t ws_size,
                              hipStream_t stream) {
    const float* X  = (const float*)d_in[0];
    const float* W1 = (const float*)d_in[1];
    const float* b1 = (const float*)d_in[2];
    const float* W2 = (const float*)d_in[3];
    const float* b2 = (const float*)d_in[4];
    const float* W3 = (const float*)d_in[5];
    const float* b3 = (const float*)d_in[6];
    const float* pa = (const float*)d_in[7];
    const int* ei   = (const int*)d_in[8];
    const int* src = ei;
    const int* dst = ei + EB;
    float* out = (float*)d_out;

    char* p = (char*)d_ws;
    int* bins    = (int*)carve(p, NB * sizeof(int));
    int* loc     = (int*)carve(p, NB * sizeof(int));
    int* blksum  = (int*)carve(p, 128 * sizeof(int));
    int* rs      = (int*)carve(p, (NB + 1) * sizeof(int));
    int* cursor  = (int*)carve(p, NB * sizeof(int));
    int2* edges  = (int2*)carve(p, EB * sizeof(int2));
    float* dinv  = (float*)carve(p, NB * sizeof(float));
    unsigned short* W1th = (unsigned short*)carve(p, DIN * H1D * 2);
    unsigned short* W1tl = (unsigned short*)carve(p, DIN * H1D * 2);
    unsigned short* W2th = (unsigned short*)carve(p, H1D * H2D * 2);
    unsigned short* W2tl = (unsigned short*)carve(p, H1D * H2D * 2);
    unsigned short* W3th = (unsigned short*)carve(p, H2D * DOUTD * 2);
    unsigned short* W3tl = (unsigned short*)carve(p, H2D * DOUTD * 2);
    // Aliased big buffers:
    // U: A1 hi/lo pair (2x10.2MB) -> R fp32 (41MB) -> T fp32 (20.5MB)
    // V: G1 hi/lo pair (2x20.5MB) -> S hi/lo pair (2x20.5MB)
    char* U = carve(p, (size_t)2 * NB * 256 * sizeof(float));
    char* V = carve(p, (size_t)2 * NB * 256 * sizeof(float));

    const int M = 2 * NB;
    unsigned short* A1h = (unsigned short*)U;
    unsigned short* A1l = A1h + (size_t)M * DIN;
    float* R = (float*)U;
    float* T = (float*)U;
    unsigned short* G1h = (unsigned short*)V;
    unsigned short* G1l = G1h + (size_t)M * H1D;
    unsigned short* Sh = (unsigned short*)V;
    unsigned short* Sl = Sh + (size_t)M * H2D;

    // --- CSR build + weight transpose/split ---
    zero_kernel<<<SCAN_BLOCKS, 256, 0, stream>>>(bins, NB);
    hist_kernel<<<(EB + 255) / 256, 256, 0, stream>>>(dst, bins);
    scanA_kernel<<<SCAN_BLOCKS, 256, 0, stream>>>(bins, loc, blksum);
    scanB_kernel<<<1, 128, 0, stream>>>(blksum);
    scanC_kernel<<<SCAN_BLOCKS, 256, 0, stream>>>(bins, loc, blksum, rs, cursor, dinv);
    scatter_kernel<<<(EB + 255) / 256, 256, 0, stream>>>(src, dst, dinv, cursor, edges);
    wcvt_kernel<<<(DIN * H1D + 255) / 256, 256, 0, stream>>>(W1, W1th, W1tl, DIN, H1D);
    wcvt_kernel<<<(H1D * H2D + 255) / 256, 256, 0, stream>>>(W2, W2th, W2tl, H1D, H2D);
    wcvt_kernel<<<(H2D * DOUTD + 255) / 256, 256, 0, stream>>>(W3, W3th, W3tl, H2D, DOUTD);

    const int AGGV = 8000;
    const int MT2 = (M + 127) / 128;  // 313

    // A1: X (batch-split) --agg--> A1 hi/lo pair [interleaved 40000 x 128]
    aggv_kernel<128, true, false, false, false, 1><<<AGGV, 256, 0, stream>>>(
        X, nullptr, A1h, A1l, rs, edges, dinv, nullptr, nullptr, 0);

    // G1: A1 @ W1 (+b1, prelu) -> G1 hi/lo pair [40000 x 256]
    gemmb_kernel<true, true, 1><<<dim3(MT2, H1D / 64), 256, 0, stream>>>(
        A1h, A1l, DIN, W1th, W1tl, H1D, b1, pa, nullptr, G1h, G1l);

    // G2: G1 @ W2 -> R fp32 [40000 x 256]
    gemmb_kernel<false, false, 0><<<dim3(MT2, H2D / 64), 256, 0, stream>>>(
        G1h, G1l, H1D, W2th, W2tl, H2D, nullptr, nullptr, R, nullptr, nullptr);

    // A2: R --agg (+b2, prelu)--> S hi/lo pair [40000 x 256], two phases
    aggv_kernel<256, false, false, true, true, 1><<<AGGV, 256, 0, stream>>>(
        R, nullptr, Sh, Sl, rs, edges, dinv, b2, pa, 0);
    aggv_kernel<256, false, false, true, true, 1><<<AGGV, 256, 0, stream>>>(
        R, nullptr, Sh, Sl, rs, edges, dinv, b2, pa, 1);

    // G3: S @ W3 -> T fp32 [40000 x 128]
    gemmb_kernel<false, false, 0><<<dim3(MT2, DOUTD / 64), 256, 0, stream>>>(
        Sh, Sl, H2D, W3th, W3tl, DOUTD, nullptr, nullptr, T, nullptr, nullptr);

    // A3: T --agg (+b3)--> out (batch-split fp32)
    aggv_kernel<128, false, true, true, false, 0><<<AGGV, 256, 0, stream>>>(
        T, out, nullptr, nullptr, rs, edges, dinv, b3, nullptr, 0);
}

// Round 12
// 418.646 us; speedup vs baseline: 1.8825x; 1.0560x over previous
//
#include <hip/hip_runtime.h>

#define NB 20000
#define EB 320000
#define DIN 128
#define H1D 256
#define H2D 256
#define DOUTD 128
#define SCAN_BLOCKS 79
#define MT64 313     // ceil(20000/64)
#define MT128 157    // ceil(20000/128)

typedef __attribute__((ext_vector_type(8))) short short8;
typedef __attribute__((ext_vector_type(4))) float f32x4;

// RNE fp32 -> bf16 hi + bf16 lo (weights only, done once).
__device__ inline void bsplit(float x, unsigned short& h, unsigned short& l) {
    unsigned u = __float_as_uint(x);
    unsigned hr = (u + 0x7FFFu + ((u >> 16) & 1u)) & 0xFFFF0000u;
    h = (unsigned short)(hr >> 16);
    float lo = x - __uint_as_float(hr);
    unsigned v = __float_as_uint(lo);
    l = (unsigned short)((v + 0x7FFFu + ((v >> 16) & 1u)) >> 16);
}

// Fast trunc split of 4 floats -> packed hi pairs + lo pairs (for A staging).
// hi = trunc16(x); lo = x - hi (exact); lo trunc'd to bf16: residual ~2^-16|x|.
__device__ inline void cvt4(float4 v, unsigned& h01, unsigned& h23,
                            unsigned& l01, unsigned& l23) {
    unsigned u0 = __float_as_uint(v.x), u1 = __float_as_uint(v.y);
    unsigned u2 = __float_as_uint(v.z), u3 = __float_as_uint(v.w);
    h01 = (u0 >> 16) | (u1 & 0xFFFF0000u);
    h23 = (u2 >> 16) | (u3 & 0xFFFF0000u);
    float f0 = v.x - __uint_as_float(u0 & 0xFFFF0000u);
    float f1 = v.y - __uint_as_float(u1 & 0xFFFF0000u);
    float f2 = v.z - __uint_as_float(u2 & 0xFFFF0000u);
    float f3 = v.w - __uint_as_float(u3 & 0xFFFF0000u);
    l01 = (__float_as_uint(f0) >> 16) | (__float_as_uint(f1) & 0xFFFF0000u);
    l23 = (__float_as_uint(f2) >> 16) | (__float_as_uint(f3) & 0xFFFF0000u);
}

// ---------------------------------------------------------------------------
// CSR build (unchanged).
// ---------------------------------------------------------------------------

__global__ void zero_kernel(int* __restrict__ p, int n) {
    int t = blockIdx.x * blockDim.x + threadIdx.x;
    if (t < n) p[t] = 0;
}

__global__ void hist_kernel(const int* __restrict__ dst, int* __restrict__ bins) {
    int t = blockIdx.x * blockDim.x + threadIdx.x;
    if (t < EB) atomicAdd(&bins[dst[t]], 1);
}

__global__ __launch_bounds__(256) void scanA_kernel(const int* __restrict__ bins,
                                                    int* __restrict__ loc,
                                                    int* __restrict__ blksum) {
    __shared__ int s[256];
    int t = threadIdx.x;
    int i = blockIdx.x * 256 + t;
    int v = (i < NB) ? bins[i] : 0;
    s[t] = v;
    __syncthreads();
    for (int off = 1; off < 256; off <<= 1) {
        int u = (t >= off) ? s[t - off] : 0;
        __syncthreads();
        s[t] += u;
        __syncthreads();
    }
    if (i < NB) loc[i] = s[t] - v;
    if (t == 255) blksum[blockIdx.x] = s[255];
}

__global__ __launch_bounds__(128) void scanB_kernel(int* __restrict__ blksum) {
    __shared__ int s[128];
    int t = threadIdx.x;
    int v = (t < SCAN_BLOCKS) ? blksum[t] : 0;
    s[t] = v;
    __syncthreads();
    for (int off = 1; off < 128; off <<= 1) {
        int u = (t >= off) ? s[t - off] : 0;
        __syncthreads();
        s[t] += u;
        __syncthreads();
    }
    if (t < SCAN_BLOCKS) blksum[t] = s[t] - v;
}

__global__ __launch_bounds__(256) void scanC_kernel(const int* __restrict__ bins,
                                                    const int* __restrict__ loc,
                                                    const int* __restrict__ blksum,
                                                    int* __restrict__ rs,
                                                    int* __restrict__ cursor,
                                                    float* __restrict__ dinv) {
    int i = blockIdx.x * 256 + threadIdx.x;
    if (i < NB) {
        int r = loc[i] + blksum[blockIdx.x];
        rs[i] = r;
        cursor[i] = r;
        dinv[i] = rsqrtf((float)bins[i] + 1.0f);
    }
    if (i == 0) rs[NB] = EB;
}

__global__ void scatter_kernel(const int* __restrict__ src, const int* __restrict__ dst,
                               const float* __restrict__ dinv,
                               int* __restrict__ cursor, int2* __restrict__ edges) {
    int t = blockIdx.x * blockDim.x + threadIdx.x;
    if (t < EB) {
        int d = dst[t], s = src[t];
        int p = atomicAdd(&cursor[d], 1);
        edges[p] = make_int2(s, __float_as_int(dinv[s] * dinv[d]));
    }
}

__global__ void wcvt_kernel(const float* __restrict__ W,
                            unsigned short* __restrict__ Wth,
                            unsigned short* __restrict__ Wtl, int K, int Nc) {
    int i = blockIdx.x * 256 + threadIdx.x;
    if (i < K * Nc) {
        int k = i / Nc, n = i % Nc;
        unsigned short h, l;
        bsplit(W[i], h, l);
        Wth[(size_t)n * K + k] = h;
        Wtl[(size_t)n * K + k] = l;
    }
}

// ---------------------------------------------------------------------------
// Per-batch sliced aggregation (pure fp32, exact R9 structure — the proven
// L2-resident gather). Virtual slice = 32 consecutive floats = one 128B line;
// 8 slices per dispatch: F=128: 4 col-slices x 2 dst-node halves; F=256:
// 8 col-slices. Slice = dispatch blockIdx&7 -> XCD; per-XCD window 2.56 MB.
// 5 nodes/wave, 8-edge unroll (4 independent chains), wave-uniform bounds.
// ---------------------------------------------------------------------------

template <int F, bool BIAS, bool PRELU>
__device__ void aggv_body(int a, int ss,
                          const float* __restrict__ h, float* __restrict__ out,
                          const int* __restrict__ rs, const int2* __restrict__ edges,
                          const float* __restrict__ dinv, const float* __restrict__ bias,
                          const float* __restrict__ pa) {
    constexpr int NS = F / 32;
    constexpr int NH = 8 / NS;
    const int half = (NH == 2) ? (ss >> 2) : 0;
    const int c32 = ss & (NS - 1);
    const int chunk = a >> 3;
    const int wid = threadIdx.x >> 6;
    const int lane = threadIdx.x & 63;
    const int li = lane & 31;
    const int eh = lane >> 5;
    const int fo = c32 * 32 + li;

    const float* gb = h + fo;
    float* ob = out + fo;
    const float pav = PRELU ? *pa : 0.0f;
    const float bval = BIAS ? bias[fo] : 0.0f;

    int n = half * (NB / NH) + chunk * 20 + wid * 5;
    int e1n = __builtin_amdgcn_readfirstlane(rs[n]);
    for (int j = 0; j < 5; ++j, ++n) {
        int e0 = e1n;
        e1n = __builtin_amdgcn_readfirstlane(rs[n + 1]);
        int e1 = e1n;
        float a0 = 0.f, a1 = 0.f, a2 = 0.f, a3 = 0.f;
        int e = e0;
        for (; e + 8 <= e1; e += 8) {
            int2 r0 = edges[e + eh];
            int2 r1 = edges[e + 2 + eh];
            int2 r2 = edges[e + 4 + eh];
            int2 r3 = edges[e + 6 + eh];
            float t0 = gb[(size_t)r0.x * F];
            float t1 = gb[(size_t)r1.x * F];
            float t2 = gb[(size_t)r2.x * F];
            float t3 = gb[(size_t)r3.x * F];
            a0 = fmaf(t0, __int_as_float(r0.y), a0);
            a1 = fmaf(t1, __int_as_float(r1.y), a1);
            a2 = fmaf(t2, __int_as_float(r2.y), a2);
            a3 = fmaf(t3, __int_as_float(r3.y), a3);
        }
        for (; e + 2 <= e1; e += 2) {
            int2 r0 = edges[e + eh];
            a0 = fmaf(gb[(size_t)r0.x * F], __int_as_float(r0.y), a0);
        }
        if (e < e1) {
            int my = e + eh;
            bool valid = (my < e1);
            int2 r0 = edges[valid ? my : e];
            float w = valid ? __int_as_float(r0.y) : 0.0f;
            a0 = fmaf(gb[(size_t)r0.x * F], w, a0);
        }
        float acc = (a0 + a1) + (a2 + a3);
        acc += __shfl_xor(acc, 32, 64);
        float dv = dinv[n];
        float r = fmaf(gb[(size_t)n * F], dv * dv, acc);
        if (BIAS) r += bval;
        if (PRELU) r = (r >= 0.0f) ? r : pav * r;
        if (eh == 0) ob[(size_t)n * F] = r;
    }
}

// ---------------------------------------------------------------------------
// bf16x3 MFMA GEMM bodies, fp32 A input (trunc-split during LDS staging).
// C = Ah*Wh + Ah*Wl + Al*Wh (fp32 acc). W pre-transposed+split [Nc][K] bf16.
// LDS rows padded to 40 shorts (80B = 5x16B: aligned b128, ~2-way banks).
// gemm64: BM=64 BN=64 BK=32, 4 waves x (1 m-tile x 4 n-tiles), ~55 VGPR ->
//   safe to fat-merge with agg (keeps full wave occupancy). NT C-stores
//   protect the co-resident agg's L2 window.
// gemm128: BM=128 (2 m-tiles/wave), for gemm-only dispatches. Cached stores.
// ---------------------------------------------------------------------------

template <bool BIAS, bool PRELU>
__device__ void gemm64_body(char* smem, int gx, const float* __restrict__ A, int K,
                            const unsigned short* __restrict__ Wth,
                            const unsigned short* __restrict__ Wtl, int Nc,
                            const float* __restrict__ bias, const float* __restrict__ pa,
                            float* __restrict__ C) {
    const int M = NB;
    unsigned short (*Ash)[40] = (unsigned short(*)[40])smem;
    unsigned short (*Asl)[40] = (unsigned short(*)[40])(smem + 5120);
    unsigned short (*Bsh)[40] = (unsigned short(*)[40])(smem + 10240);
    unsigned short (*Bsl)[40] = (unsigned short(*)[40])(smem + 15360);
    const int t = threadIdx.x;
    const int bm = (gx % MT64) * 64;
    const int bn = (gx / MT64) * 64;
    const int w = t >> 6, l = t & 63, lm = l & 15, lg = l >> 4;
    const int lk = lg * 8;
    const int sr = t >> 2, sc = (t & 3) * 8;

    f32x4 acc[4];
#pragma unroll
    for (int nt = 0; nt < 4; ++nt) acc[nt] = (f32x4){0.f, 0.f, 0.f, 0.f};

    for (int k0 = 0; k0 < K; k0 += 32) {
        float4 va = make_float4(0.f, 0.f, 0.f, 0.f), vb = va;
        int gr = bm + sr;
        if (gr < M) {
            va = *(const float4*)&A[(size_t)gr * K + k0 + sc];
            vb = *(const float4*)&A[(size_t)gr * K + k0 + sc + 4];
        }
        unsigned h01, h23, l01, l23, h45, h67, l45, l67;
        cvt4(va, h01, h23, l01, l23);
        cvt4(vb, h45, h67, l45, l67);
        *(uint4*)&Ash[sr][sc] = make_uint4(h01, h23, h45, h67);
        *(uint4*)&Asl[sr][sc] = make_uint4(l01, l23, l45, l67);
        *(short8*)&Bsh[sr][sc] = *(const short8*)&Wth[(size_t)(bn + sr) * K + k0 + sc];
        *(short8*)&Bsl[sr][sc] = *(const short8*)&Wtl[(size_t)(bn + sr) * K + k0 + sc];
        __syncthreads();
        short8 ah = *(const short8*)&Ash[w * 16 + lm][lk];
        short8 al = *(const short8*)&Asl[w * 16 + lm][lk];
#pragma unroll
        for (int nt = 0; nt < 4; ++nt) {
            short8 bh = *(const short8*)&Bsh[nt * 16 + lm][lk];
            short8 bl = *(const short8*)&Bsl[nt * 16 + lm][lk];
            acc[nt] = __builtin_amdgcn_mfma_f32_16x16x32_bf16(ah, bh, acc[nt], 0, 0, 0);
            acc[nt] = __builtin_amdgcn_mfma_f32_16x16x32_bf16(ah, bl, acc[nt], 0, 0, 0);
            acc[nt] = __builtin_amdgcn_mfma_f32_16x16x32_bf16(al, bh, acc[nt], 0, 0, 0);
        }
        __syncthreads();
    }

    const float pav = PRELU ? *pa : 0.0f;
#pragma unroll
    for (int nt = 0; nt < 4; ++nt) {
        int col = bn + nt * 16 + lm;
        float bv = BIAS ? bias[col] : 0.0f;
#pragma unroll
        for (int j = 0; j < 4; ++j) {
            int row = bm + w * 16 + lg * 4 + j;
            if (row < M) {
                float r = acc[nt][j] + bv;
                if (PRELU) r = (r >= 0.0f) ? r : pav * r;
                __builtin_nontemporal_store(r, &C[(size_t)row * Nc + col]);
            }
        }
    }
}

template <bool BIAS, bool PRELU>
__device__ void gemm128_body(char* smem, int gx, const float* __restrict__ A, int K,
                             const unsigned short* __restrict__ Wth,
                             const unsigned short* __restrict__ Wtl, int Nc,
                             const float* __restrict__ bias, const float* __restrict__ pa,
                             float* __restrict__ C) {
    const int M = NB;
    unsigned short (*Ash)[40] = (unsigned short(*)[40])smem;
    unsigned short (*Asl)[40] = (unsigned short(*)[40])(smem + 10240);
    unsigned short (*Bsh)[40] = (unsigned short(*)[40])(smem + 20480);
    unsigned short (*Bsl)[40] = (unsigned short(*)[40])(smem + 25600);
    const int t = threadIdx.x;
    const int bm = (gx % MT128) * 128;
    const int bn = (gx / MT128) * 64;
    const int w = t >> 6, l = t & 63, lm = l & 15, lg = l >> 4;
    const int lk = lg * 8;
    const int ar = t >> 1, ac = (t & 1) * 16;
    const int br = t >> 2, bc = (t & 3) * 8;

    f32x4 acc[2][4];
#pragma unroll
    for (int m = 0; m < 2; ++m)
#pragma unroll
        for (int nt = 0; nt < 4; ++nt) acc[m][nt] = (f32x4){0.f, 0.f, 0.f, 0.f};

    for (int k0 = 0; k0 < K; k0 += 32) {
        int gr = bm + ar;
#pragma unroll
        for (int hseg = 0; hseg < 2; ++hseg) {
            int cc = ac + hseg * 8;
            float4 va = make_float4(0.f, 0.f, 0.f, 0.f), vb = va;
            if (gr < M) {
                va = *(const float4*)&A[(size_t)gr * K + k0 + cc];
                vb = *(const float4*)&A[(size_t)gr * K + k0 + cc + 4];
            }
            unsigned h01, h23, l01, l23, h45, h67, l45, l67;
            cvt4(va, h01, h23, l01, l23);
            cvt4(vb, h45, h67, l45, l67);
            *(uint4*)&Ash[ar][cc] = make_uint4(h01, h23, h45, h67);
            *(uint4*)&Asl[ar][cc] = make_uint4(l01, l23, l45, l67);
        }
        *(short8*)&Bsh[br][bc] = *(const short8*)&Wth[(size_t)(bn + br) * K + k0 + bc];
        *(short8*)&Bsl[br][bc] = *(const short8*)&Wtl[(size_t)(bn + br) * K + k0 + bc];
        __syncthreads();
        short8 ah0 = *(const short8*)&Ash[w * 32 + lm][lk];
        short8 ah1 = *(const short8*)&Ash[w * 32 + 16 + lm][lk];
        short8 al0 = *(const short8*)&Asl[w * 32 + lm][lk];
        short8 al1 = *(const short8*)&Asl[w * 32 + 16 + lm][lk];
#pragma unroll
        for (int nt = 0; nt < 4; ++nt) {
            short8 bh = *(const short8*)&Bsh[nt * 16 + lm][lk];
            short8 bl = *(const short8*)&Bsl[nt * 16 + lm][lk];
            acc[0][nt] = __builtin_amdgcn_mfma_f32_16x16x32_bf16(ah0, bh, acc[0][nt], 0, 0, 0);
            acc[0][nt] = __builtin_amdgcn_mfma_f32_16x16x32_bf16(ah0, bl, acc[0][nt], 0, 0, 0);
            acc[0][nt] = __builtin_amdgcn_mfma_f32_16x16x32_bf16(al0, bh, acc[0][nt], 0, 0, 0);
            acc[1][nt] = __builtin_amdgcn_mfma_f32_16x16x32_bf16(ah1, bh, acc[1][nt], 0, 0, 0);
            acc[1][nt] = __builtin_amdgcn_mfma_f32_16x16x32_bf16(ah1, bl, acc[1][nt], 0, 0, 0);
            acc[1][nt] = __builtin_amdgcn_mfma_f32_16x16x32_bf16(al1, bh, acc[1][nt], 0, 0, 0);
        }
        __syncthreads();
    }

    const float pav = PRELU ? *pa : 0.0f;
#pragma unroll
    for (int m = 0; m < 2; ++m) {
#pragma unroll
        for (int nt = 0; nt < 4; ++nt) {
            int col = bn + nt * 16 + lm;
            float bv = BIAS ? bias[col] : 0.0f;
#pragma unroll
            for (int j = 0; j < 4; ++j) {
                int row = bm + w * 32 + m * 16 + lg * 4 + j;
                if (row < M) {
                    float r = acc[m][nt][j] + bv;
                    if (PRELU) r = (r >= 0.0f) ? r : pav * r;
                    C[(size_t)row * Nc + col] = r;
                }
            }
        }
    }
}

// ---------------------------------------------------------------------------
// Wrappers. fat64: gemm64 blocks first (bx < ng), agg tail (slice = bx&7 so
// the XCD binding survives; (chunk,slice) coverage is bijective per 8-group).
// gemm2: two gemm128 ranges in one dispatch.
// ---------------------------------------------------------------------------

template <int F, bool BIAS, bool PRELU>
__global__ __launch_bounds__(256) void aggv_kernel(
    const float* __restrict__ h, float* __restrict__ out,
    const int* __restrict__ rs, const int2* __restrict__ edges,
    const float* __restrict__ dinv, const float* __restrict__ bias,
    const float* __restrict__ pa) {
    aggv_body<F, BIAS, PRELU>(blockIdx.x, blockIdx.x & 7, h, out, rs, edges,
                              dinv, bias, pa);
}

template <int AF, bool AB, bool AP, bool GB_, bool GP>
__global__ __launch_bounds__(256) void fat64_kernel(
    const float* __restrict__ A, int K,
    const unsigned short* __restrict__ Wth, const unsigned short* __restrict__ Wtl,
    int Nc, const float* __restrict__ gbias, float* __restrict__ C, int ng,
    const float* __restrict__ ah, float* __restrict__ aout,
    const int* __restrict__ rs, const int2* __restrict__ edges,
    const float* __restrict__ dinv, const float* __restrict__ abias,
    const float* __restrict__ pa) {
    __shared__ char smem[20480];
    int bx = blockIdx.x;
    if (bx < ng) {
        gemm64_body<GB_, GP>(smem, bx, A, K, Wth, Wtl, Nc, gbias, pa, C);
    } else {
        aggv_body<AF, AB, AP>(bx - ng, bx & 7, ah, aout, rs, edges, dinv, abias, pa);
    }
}

template <bool B1, bool P1, bool B2, bool P2>
__global__ __launch_bounds__(256) void gemm2_kernel(
    const float* __restrict__ A1p, int K1,
    const unsigned short* __restrict__ W1h, const unsigned short* __restrict__ W1l,
    int N1, const float* __restrict__ bias1, float* __restrict__ C1, int ng1,
    const float* __restrict__ A2p, int K2,
    const unsigned short* __restrict__ W2h, const unsigned short* __restrict__ W2l,
    int N2, const float* __restrict__ bias2, float* __restrict__ C2,
    const float* __restrict__ pa) {
    __shared__ char smem[30720];
    int bx = blockIdx.x;
    if (bx < ng1) gemm128_body<B1, P1>(smem, bx, A1p, K1, W1h, W1l, N1, bias1, pa, C1);
    else          gemm128_body<B2, P2>(smem, bx - ng1, A2p, K2, W2h, W2l, N2, bias2, pa, C2);
}

// ---------------------------------------------------------------------------

static inline char* carve(char*& p, size_t bytes) {
    char* r = p;
    p += (bytes + 255) & ~(size_t)255;
    return r;
}

extern "C" void kernel_launch(void* const* d_in, const int* in_sizes, int n_in,
                              void* d_out, int out_size, void* d_ws, size_t ws_size,
                              hipStream_t stream) {
    const float* X  = (const float*)d_in[0];
    const float* W1 = (const float*)d_in[1];
    const float* b1 = (const float*)d_in[2];
    const float* W2 = (const float*)d_in[3];
    const float* b2 = (const float*)d_in[4];
    const float* W3 = (const float*)d_in[5];
    const float* b3 = (const float*)d_in[6];
    const float* pa = (const float*)d_in[7];
    const int* ei   = (const int*)d_in[8];
    const int* src = ei;
    const int* dst = ei + EB;
    float* out = (float*)d_out;

    char* p = (char*)d_ws;
    int* bins    = (int*)carve(p, NB * sizeof(int));
    int* loc     = (int*)carve(p, NB * sizeof(int));
    int* blksum  = (int*)carve(p, 128 * sizeof(int));
    int* rs      = (int*)carve(p, (NB + 1) * sizeof(int));
    int* cursor  = (int*)carve(p, NB * sizeof(int));
    int2* edges  = (int2*)carve(p, EB * sizeof(int2));
    float* dinv  = (float*)carve(p, NB * sizeof(float));
    unsigned short* W1th = (unsigned short*)carve(p, DIN * H1D * 2);
    unsigned short* W1tl = (unsigned short*)carve(p, DIN * H1D * 2);
    unsigned short* W2th = (unsigned short*)carve(p, H1D * H2D * 2);
    unsigned short* W2tl = (unsigned short*)carve(p, H1D * H2D * 2);
    unsigned short* W3th = (unsigned short*)carve(p, H2D * DOUTD * 2);
    unsigned short* W3tl = (unsigned short*)carve(p, H2D * DOUTD * 2);
    float* P0 = (float*)carve(p, (size_t)NB * DIN * sizeof(float));   // 10.24 MB
    float* P1 = (float*)carve(p, (size_t)NB * DIN * sizeof(float));
    float* Q0 = (float*)carve(p, (size_t)NB * H1D * sizeof(float));   // 20.48 MB
    float* Q1 = (float*)carve(p, (size_t)NB * H1D * sizeof(float));
    float* R1 = (float*)carve(p, (size_t)NB * H2D * sizeof(float));
    // Aliases: R0 = d_out (20.48 MB, dead before final output writes);
    // S0=Q0, S1=Q1, T0=P0, T1=P1 (producer/consumer lifetimes verified).
    float* R0 = (float*)d_out;
    float* S0 = Q0; float* S1 = Q1;
    float* T0 = P0; float* T1 = P1;

    const float* X0 = X;
    const float* X1 = X + (size_t)NB * DIN;
    float* out0 = out;
    float* out1 = out + (size_t)NB * DOUTD;

    // --- CSR + weight split ---
    zero_kernel<<<SCAN_BLOCKS, 256, 0, stream>>>(bins, NB);
    hist_kernel<<<(EB + 255) / 256, 256, 0, stream>>>(dst, bins);
    scanA_kernel<<<SCAN_BLOCKS, 256, 0, stream>>>(bins, loc, blksum);
    scanB_kernel<<<1, 128, 0, stream>>>(blksum);
    scanC_kernel<<<SCAN_BLOCKS, 256, 0, stream>>>(bins, loc, blksum, rs, cursor, dinv);
    scatter_kernel<<<(EB + 255) / 256, 256, 0, stream>>>(src, dst, dinv, cursor, edges);
    wcvt_kernel<<<(DIN * H1D + 255) / 256, 256, 0, stream>>>(W1, W1th, W1tl, DIN, H1D);
    wcvt_kernel<<<(H1D * H2D + 255) / 256, 256, 0, stream>>>(W2, W2th, W2tl, H1D, H2D);
    wcvt_kernel<<<(H2D * DOUTD + 255) / 256, 256, 0, stream>>>(W3, W3th, W3tl, H2D, DOUTD);

    const int NA128 = 4000;               // 500 chunks x 8 slices
    const int NA256 = 8000;               // 1000 chunks x 8 slices
    const int NG1_64 = MT64 * (H1D / 64); // 1252
    const int NG2_64 = MT64 * (H2D / 64); // 1252
    const int NG3_64 = MT64 * (DOUTD / 64); // 626
    const int NG2_128 = MT128 * (H2D / 64); // 628
    const int NG1_128 = MT128 * (H1D / 64); // 628

    // Stagger: b0 = A1 G1 G2 A2 G3 A3 ; b1 lags one stage, paired into fats.

    // D1: A1(b0): X0 -> P0
    aggv_kernel<128, false, false><<<NA128, 256, 0, stream>>>(
        X0, P0, rs, edges, dinv, nullptr, nullptr);

    // D2: G1(b0): P0@W1(+b1,prelu) -> Q0  ||  A1(b1): X1 -> P1
    fat64_kernel<128, false, false, true, true><<<NG1_64 + NA128, 256, 0, stream>>>(
        P0, DIN, W1th, W1tl, H1D, b1, Q0, NG1_64,
        X1, P1, rs, edges, dinv, nullptr, pa);

    // D3: G2(b0): Q0@W2 -> R0(=d_out)  ;  G1(b1): P1@W1(+b1,prelu) -> Q1
    gemm2_kernel<false, false, true, true><<<NG2_128 + NG1_128, 256, 0, stream>>>(
        Q0, H1D, W2th, W2tl, H2D, nullptr, R0, NG2_128,
        P1, DIN, W1th, W1tl, H1D, b1, Q1, pa);

    // D4: G2(b1): Q1@W2 -> R1  ||  A2(b0): R0 -> S0(=Q0) (+b2,prelu)
    fat64_kernel<256, true, true, false, false><<<NG2_64 + NA256, 256, 0, stream>>>(
        Q1, H1D, W2th, W2tl, H2D, nullptr, R1, NG2_64,
        R0, S0, rs, edges, dinv, b2, pa);

    // D5: G3(b0): S0@W3 -> T0(=P0)  ||  A2(b1): R1 -> S1(=Q1) (+b2,prelu)
    fat64_kernel<256, true, true, false, false><<<NG3_64 + NA256, 256, 0, stream>>>(
        S0, H2D, W3th, W3tl, DOUTD, nullptr, T0, NG3_64,
        R1, S1, rs, edges, dinv, b2, pa);

    // D6: G3(b1): S1@W3 -> T1(=P1)  ||  A3(b0): T0 -> out0 (+b3)
    fat64_kernel<128, true, false, false, false><<<NG3_64 + NA128, 256, 0, stream>>>(
        S1, H2D, W3th, W3tl, DOUTD, nullptr, T1, NG3_64,
        T0, out0, rs, edges, dinv, b3, pa);

    // D7: A3(b1): T1 -> out1 (+b3)
    aggv_kernel<128, true, false><<<NA128, 256, 0, stream>>>(
        T1, out1, rs, edges, dinv, b3, nullptr);
}